// Round 1
// baseline (144.018 us; speedup 1.0000x reference)
//
#include <hip/hip_runtime.h>
#include <math.h>

// Problem constants
#define BB   4
#define CC   128
#define HH   64
#define WW   64
#define OUTC 128
#define KK   25   // 5x5 attention taps

typedef __attribute__((ext_vector_type(8))) short short8;   // 8 bf16
typedef __attribute__((ext_vector_type(4))) float floatx4;  // MFMA acc

__device__ __forceinline__ unsigned short f32_to_bf16(float v) {
    unsigned int u = __float_as_uint(v);
    u += 0x7fffu + ((u >> 16) & 1u);          // RNE
    return (unsigned short)(u >> 16);
}

// ---------------------------------------------------------------------------
// Kernel 0 (prep):
//  i < 16384:  w2o[o][c] = bf16( sum_r w2[o, c*4+r] )        (o-major)
//  else:       w1t[c][kk][9] = w1[kk][c][9]   (225 contiguous dwords per c,
//              so the fused kernel's per-channel weight reads are one
//              wave-uniform 225-dword block -> s_load)
// ---------------------------------------------------------------------------
__global__ void prep_kernel(const float* __restrict__ w2,
                            const float* __restrict__ w1,
                            unsigned short* __restrict__ w2o,
                            float* __restrict__ w1t) {
    int i = blockIdx.x * 256 + threadIdx.x;
    if (i < 16384) {
        int o = i >> 7, c = i & 127;
        const float* p = w2 + o * (4 * CC) + c * 4;
        w2o[o * CC + c] = f32_to_bf16(p[0] + p[1] + p[2] + p[3]);
    } else if (i < 16384 + 28800) {
        int j  = i - 16384;
        int jj = j % 9;
        int r  = j / 9;
        int kk = r % 25;
        int c  = r / 25;
        w1t[c * 225 + kk * 9 + jj] = w1[((size_t)kk * CC + c) * 9 + jj];
    }
}

// ---------------------------------------------------------------------------
// Fused kernel: conv1 (3x3) + softmax + local attention + MFMA + 2x2 store.
// grid 256 = (b, h): one full 64-px row per block, 512 threads (8 waves).
//  conv1 : wave wv owns channels [16wv,16wv+16), lane = px. Weights are
//          wave-uniform (readfirstlane) -> SGPR loads; 9 x-taps in VGPRs
//          feed all 25 taps (450 FMA / 9 loads). Partials merged via
//          ds_add_f32 LDS atomics (8 waves x 25 -> ~200 atomic instrs).
//  phase C: 8 chunks of 16 c, x tile staged via regs (issue next chunk's
//          loads before computing current = T14 async-stage split).
//  MFMA  : C[128 o][64 px], 8 waves = 4(mq) x 2(nh), 2x2 16x16 tiles each.
// ---------------------------------------------------------------------------
__global__ __launch_bounds__(512, 2) void fused_kernel(
        const float* __restrict__ x,
        const float* __restrict__ w1t,
        const unsigned short* __restrict__ w2o,
        const float* __restrict__ b1,
        const float* __restrict__ b2,
        float* __restrict__ out) {
    __shared__ float pk[KK * 64];               // logits -> probs   6.4 KB
    __shared__ float xld[16 * 5 * 68];          // x chunk tile     21.8 KB
    __shared__ unsigned short sKT[64 * 136];    // s bf16 [px][c]   17.4 KB

    // XCD-aware swizzle (grid 256 % 8 == 0 -> bijective): contiguous
    // 32-row h-chunks per XCD so x rows / w1t stay L2-resident.
    int bid0 = blockIdx.x;
    int bid  = (bid0 & 7) * 32 + (bid0 >> 3);
    int h = bid & 63;
    int b = bid >> 6;
    int t = threadIdx.x;
    int lane = t & 63;
    int wv = __builtin_amdgcn_readfirstlane(t >> 6);   // wave id 0..7 (SGPR)

    // ---- init logits with conv1 bias ----
    for (int i = t; i < KK * 64; i += 512) pk[i] = b1[i >> 6];
    __syncthreads();

    // ---- conv1 3x3 SAME: lane = px, wave = 16-channel slice ----
    int px = lane;
    float mt = (h > 0) ? 1.f : 0.f, mb = (h < HH - 1) ? 1.f : 0.f;
    float ml = (px > 0) ? 1.f : 0.f, mr = (px < WW - 1) ? 1.f : 0.f;
    int ya = (h > 0) ? h - 1 : 0;
    int yb = (h < HH - 1) ? h + 1 : HH - 1;
    int xl = (px > 0) ? px - 1 : 0;
    int xr = (px < WW - 1) ? px + 1 : WW - 1;

    float acc[KK];
    #pragma unroll
    for (int k = 0; k < KK; ++k) acc[k] = 0.f;

    const float* xb = x + (size_t)b * CC * (HH * WW);
    #pragma unroll 2
    for (int cc = 0; cc < 16; ++cc) {
        int c = wv * 16 + cc;
        const float* xp = xb + (size_t)c * (HH * WW);
        const float* r0 = xp + ya * WW;
        const float* r1 = xp + h  * WW;
        const float* r2 = xp + yb * WW;
        float x00 = r0[xl] * (mt * ml), x01 = r0[px] * mt, x02 = r0[xr] * (mt * mr);
        float x10 = r1[xl] * ml,        x11 = r1[px],      x12 = r1[xr] * mr;
        float x20 = r2[xl] * (mb * ml), x21 = r2[px] * mb, x22 = r2[xr] * (mb * mr);
        const float* wc = w1t + c * 225;     // wave-uniform -> s_load
        #pragma unroll
        for (int kk = 0; kk < KK; ++kk) {
            const float* wq = wc + kk * 9;
            acc[kk] += x00 * wq[0] + x01 * wq[1] + x02 * wq[2]
                     + x10 * wq[3] + x11 * wq[4] + x12 * wq[5]
                     + x20 * wq[6] + x21 * wq[7] + x22 * wq[8];
        }
    }
    // merge 8 wave-partials (64 px distinct addrs/wave -> conflict-free)
    #pragma unroll
    for (int k = 0; k < KK; ++k)
        atomicAdd(&pk[k * 64 + px], acc[k]);
    __syncthreads();

    // ---- softmax over the 25 taps (wave 0, one px per lane) ----
    if (t < 64) {
        float mx = -1e30f;
        for (int k = 0; k < KK; ++k) mx = fmaxf(mx, pk[k * 64 + t]);
        float s = 0.f;
        for (int k = 0; k < KK; ++k) {
            float e = __expf(pk[k * 64 + t] - mx);
            pk[k * 64 + t] = e;
            s += e;
        }
        float inv = 1.f / s;
        for (int k = 0; k < KK; ++k) pk[k * 64 + t] *= inv;
    }
    __syncthreads();

    // ---- phase C: s[c][px] = sum_k p[k][px] * xwin ----
    // thread = (pp = t&31 -> pixels {2pp,2pp+1}, cl = t>>5 -> 1 c per chunk)
    int pp = t & 31, cl = t >> 5;
    float2 p01[KK];
    #pragma unroll
    for (int k = 0; k < KK; ++k)
        p01[k] = *(const float2*)&pk[k * 64 + 2 * pp];

    // staging descriptors are chunk-invariant: precompute once
    int soff[11]; float smsk[11]; int scl[11];
    #pragma unroll
    for (int j = 0; j < 11; ++j) {
        int i  = t + j * 512;
        int ii = (i < 5440) ? i : 0;
        int c_  = ii / 340;
        int rem = ii - c_ * 340;
        int di  = rem / 68;
        int col = rem - di * 68;
        int y  = h + di - 2;
        int xc = col - 2;
        bool inb = (i < 5440) && (y >= 0) && (y < HH) && (xc >= 0) && (xc < WW);
        int yc  = min(max(y, 0), HH - 1);
        int xcc = min(max(xc, 0), WW - 1);
        scl[j]  = c_;
        soff[j] = yc * WW + xcc;
        smsk[j] = inb ? 1.f : 0.f;
    }

    float stg[11];
    #pragma unroll
    for (int j = 0; j < 11; ++j)            // preload chunk 0
        stg[j] = xb[(size_t)scl[j] * (HH * WW) + soff[j]] * smsk[j];

    for (int ch = 0; ch < 8; ++ch) {
        __syncthreads();                    // xld free
        #pragma unroll
        for (int j = 0; j < 11; ++j) {
            int i = t + j * 512;
            if (i < 5440) xld[i] = stg[j];
        }
        __syncthreads();                    // xld ready
        if (ch < 7) {                       // issue next chunk's loads early
            #pragma unroll
            for (int j = 0; j < 11; ++j)
                stg[j] = xb[(size_t)((ch + 1) * 16 + scl[j]) * (HH * WW)
                            + soff[j]] * smsk[j];
        }
        // batch the 15 b64 LDS loads, then the 50 FMAs
        const float* xr_ = &xld[(cl * 5) * 68 + 2 * pp];
        float2 xv[15];
        #pragma unroll
        for (int di = 0; di < 5; ++di) {
            xv[di * 3 + 0] = *(const float2*)(xr_ + di * 68);
            xv[di * 3 + 1] = *(const float2*)(xr_ + di * 68 + 2);
            xv[di * 3 + 2] = *(const float2*)(xr_ + di * 68 + 4);
        }
        float a0 = 0.f, a1 = 0.f;
        #pragma unroll
        for (int di = 0; di < 5; ++di) {
            float2 x01 = xv[di * 3 + 0];
            float2 x23 = xv[di * 3 + 1];
            float2 x45 = xv[di * 3 + 2];
            a0 += p01[di*5+0].x * x01.x + p01[di*5+1].x * x01.y
                + p01[di*5+2].x * x23.x + p01[di*5+3].x * x23.y
                + p01[di*5+4].x * x45.x;
            a1 += p01[di*5+0].y * x01.y + p01[di*5+1].y * x23.x
                + p01[di*5+2].y * x23.y + p01[di*5+3].y * x45.x
                + p01[di*5+4].y * x45.y;
        }
        int c = ch * 16 + cl;
        sKT[(2 * pp) * 136 + c]     = f32_to_bf16(a0);
        sKT[(2 * pp + 1) * 136 + c] = f32_to_bf16(a1);
    }
    __syncthreads();

    // ---- MFMA: C[o][px] = sum_c W2s[o][c] * s[c][px] ----
    int fpx = lane & 15, quad = lane >> 4;
    int mq = wv & 3, nh = wv >> 2;
    floatx4 am[2][2] = {{{0.f,0.f,0.f,0.f},{0.f,0.f,0.f,0.f}},
                        {{0.f,0.f,0.f,0.f},{0.f,0.f,0.f,0.f}}};
    #pragma unroll
    for (int ks = 0; ks < 4; ++ks) {
        short8 bf0 = *(const short8*)&sKT[(32*nh      + fpx) * 136 + ks*32 + quad*8];
        short8 bf1 = *(const short8*)&sKT[(32*nh + 16 + fpx) * 136 + ks*32 + quad*8];
        short8 af0 = *(const short8*)&w2o[(size_t)(32*mq      + fpx) * CC + ks*32 + quad*8];
        short8 af1 = *(const short8*)&w2o[(size_t)(32*mq + 16 + fpx) * CC + ks*32 + quad*8];
        am[0][0] = __builtin_amdgcn_mfma_f32_16x16x32_bf16(af0, bf0, am[0][0], 0, 0, 0);
        am[0][1] = __builtin_amdgcn_mfma_f32_16x16x32_bf16(af0, bf1, am[0][1], 0, 0, 0);
        am[1][0] = __builtin_amdgcn_mfma_f32_16x16x32_bf16(af1, bf0, am[1][0], 0, 0, 0);
        am[1][1] = __builtin_amdgcn_mfma_f32_16x16x32_bf16(af1, bf1, am[1][1], 0, 0, 0);
    }

    // ---- epilogue: D[row=quad*4+reg][col=fpx] + b2, 2x2-replicated write ----
    float* ob = out + (size_t)b * OUTC * (4 * HH * WW);
    int y0 = 2 * h;
    #pragma unroll
    for (int mt2 = 0; mt2 < 2; ++mt2) {
        #pragma unroll
        for (int nt = 0; nt < 2; ++nt) {
            #pragma unroll
            for (int reg = 0; reg < 4; ++reg) {
                int o   = 32*mq + 16*mt2 + quad*4 + reg;
                int pxo = 32*nh + 16*nt + fpx;
                float v = am[mt2][nt][reg] + b2[o];
                float2 v2 = make_float2(v, v);
                float* r0p = ob + ((size_t)o * (2*HH) + y0) * (2*WW) + 2*pxo;
                *(float2*)(r0p)        = v2;
                *(float2*)(r0p + 2*WW) = v2;
            }
        }
    }
}

// ---------------------------------------------------------------------------
extern "C" void kernel_launch(void* const* d_in, const int* in_sizes, int n_in,
                              void* d_out, int out_size, void* d_ws, size_t ws_size,
                              hipStream_t stream) {
    const float* x  = (const float*)d_in[0];
    const float* w1 = (const float*)d_in[1];
    const float* b1 = (const float*)d_in[2];
    const float* w2 = (const float*)d_in[3];
    const float* b2 = (const float*)d_in[4];
    float* out = (float*)d_out;

    unsigned short* w2o = (unsigned short*)d_ws;               // 32 KB
    float* w1t = (float*)(w2o + (size_t)OUTC * CC);            // 115 KB

    prep_kernel<<<(16384 + 28800 + 255) / 256, 256, 0, stream>>>(w2, w1, w2o, w1t);
    fused_kernel<<<BB * HH, 512, 0, stream>>>(x, w1t, w2o, b1, b2, out);
}